// Round 1
// baseline (544.142 us; speedup 1.0000x reference)
//
#include <hip/hip_runtime.h>
#include <cstdint>
#include <cstddef>

// Problem: B=128, S=512, H=512
//   context[b,h] = sum_s softmax_s( sum_k tanh(u[b,s,k]) Ve[k] ) * h[b,s,h]
//   u = h@U1a^T + x@U2^T + (h_last@U1b^T broadcast over s)
// Strategy: fp16 MFMA GEMM (M=65536, N=512, K=1024 concat) with fused
// tanh/Ve epilogue -> e[b,s]; then softmax; then context pass.

typedef _Float16 h8 __attribute__((ext_vector_type(8)));
typedef float    f4 __attribute__((ext_vector_type(4)));

// ---------------------------------------------------------------------------
// Setup: pack [U1a | U2] as fp16 row-major Bws[512 n][1024 k]
// ---------------------------------------------------------------------------
__global__ void bsetup_kernel(const float* __restrict__ U1, const float* __restrict__ U2,
                              _Float16* __restrict__ Bws) {
  int g = blockIdx.x * 256 + threadIdx.x;   // 65536 threads, one 8-elem slot each
  int n = g >> 7;
  int k0 = (g & 127) * 8;
  float v[8];
  if (k0 < 512) {
    const float* p = U1 + (size_t)n * 1024 + k0;       // U1a[n][k0..k0+7]
    float4 a = *(const float4*)p; float4 b = *(const float4*)(p + 4);
    v[0]=a.x; v[1]=a.y; v[2]=a.z; v[3]=a.w; v[4]=b.x; v[5]=b.y; v[6]=b.z; v[7]=b.w;
  } else {
    const float* p = U2 + (size_t)n * 512 + (k0 - 512); // U2[n][k0-512..]
    float4 a = *(const float4*)p; float4 b = *(const float4*)(p + 4);
    v[0]=a.x; v[1]=a.y; v[2]=a.z; v[3]=a.w; v[4]=b.x; v[5]=b.y; v[6]=b.z; v[7]=b.w;
  }
  _Float16 hv[8];
#pragma unroll
  for (int j = 0; j < 8; ++j) hv[j] = (_Float16)v[j];
  *(uint4*)(Bws + (size_t)n * 1024 + k0) = *(uint4*)hv;
}

// ---------------------------------------------------------------------------
// bias[b][n] = sum_h h[b][S-1][h] * U1[n][512+h]   (fp32, exact)
// ---------------------------------------------------------------------------
__global__ void bias_kernel(const float* __restrict__ hT, const float* __restrict__ U1,
                            float* __restrict__ bias) {
  const int b = blockIdx.x, t = threadIdx.x;
  const int l = t & 63, w = t >> 6;
  __shared__ float4 hl[128];
  if (t < 128) hl[t] = *(const float4*)(hT + ((size_t)b * 512 + 511) * 512 + t * 4);
  __syncthreads();
  for (int n = w; n < 512; n += 4) {
    const float4* ur = (const float4*)(U1 + (size_t)n * 1024 + 512);
    float4 u0 = ur[l],      u1 = ur[l + 64];
    float4 h0 = hl[l],      h1 = hl[l + 64];
    float s = u0.x*h0.x + u0.y*h0.y + u0.z*h0.z + u0.w*h0.w
            + u1.x*h1.x + u1.y*h1.y + u1.z*h1.z + u1.w*h1.w;
#pragma unroll
    for (int d = 1; d < 64; d <<= 1) s += __shfl_xor(s, d, 64);
    if (l == 0) bias[(size_t)b * 512 + n] = s;
  }
}

// ---------------------------------------------------------------------------
// Main fused GEMM: e[row] += sum_{n in tile} tanh(acc + bias) * Ve[n]
// BM=64, BN=256, BK=64. 256 threads = 4 waves, wave tile 64x64 (4x4 frags).
// ---------------------------------------------------------------------------
__global__ __launch_bounds__(256, 3)
void gemm_kernel(const float* __restrict__ hT, const float* __restrict__ xT,
                 const _Float16* __restrict__ Bws, const float* __restrict__ bias,
                 const float* __restrict__ Ve, float* __restrict__ e) {
  const int bm    = blockIdx.x >> 1;
  const int nt    = blockIdx.x & 1;
  const int row0  = bm * 64;          // global M row (= b*512 + s)
  const int bb    = row0 >> 9;        // batch index
  const int ncol0 = nt * 256;
  const int t   = threadIdx.x;
  const int l   = t & 63;
  const int wv  = t >> 6;
  const int l15 = l & 15;
  const int lhi = l >> 4;

  __shared__ __align__(16) _Float16 Asm[64][72];   // 144 B rows (padded: 2-way max)
  __shared__ __align__(16) _Float16 Bsm[256][64];  // 128 B rows, slot-XOR swizzled

  float4 av[4];
  uint4  bv[8];

  auto LA = [&](int kt) {
    const float* src = (kt < 8) ? hT : xT;
    const int kc = (kt & 7) * 64;
#pragma unroll
    for (int i = 0; i < 4; ++i) {
      int g = i * 256 + t;
      int r = g >> 4, c4 = g & 15;
      av[i] = *(const float4*)(src + (size_t)(row0 + r) * 512 + kc + c4 * 4);
    }
  };
  auto LB = [&](int kt) {
#pragma unroll
    for (int i = 0; i < 8; ++i) {
      int g = i * 256 + t;
      int r = g >> 3, s = g & 7;
      bv[i] = *(const uint4*)(Bws + (size_t)(ncol0 + r) * 1024 + kt * 64 + s * 8);
    }
  };

  f4 acc[4][4];
#pragma unroll
  for (int mf = 0; mf < 4; ++mf)
#pragma unroll
    for (int nf = 0; nf < 4; ++nf)
      acc[mf][nf] = (f4){0.f, 0.f, 0.f, 0.f};

  LA(0); LB(0);

  for (int kt = 0; kt < 16; ++kt) {
    // regs -> LDS (A converted to fp16; B swizzled by 16B slot)
#pragma unroll
    for (int i = 0; i < 4; ++i) {
      int g = i * 256 + t; int r = g >> 4, c4 = g & 15;
      _Float16 hv[4];
      hv[0] = (_Float16)av[i].x; hv[1] = (_Float16)av[i].y;
      hv[2] = (_Float16)av[i].z; hv[3] = (_Float16)av[i].w;
      *(uint2*)&Asm[r][c4 * 4] = *(uint2*)hv;
    }
#pragma unroll
    for (int i = 0; i < 8; ++i) {
      int g = i * 256 + t; int r = g >> 3, s = g & 7;
      *(uint4*)&Bsm[r][(s ^ (r & 7)) * 8] = bv[i];
    }
    __syncthreads();
    if (kt < 15) { LA(kt + 1); LB(kt + 1); }   // prefetch under MFMA phase
#pragma unroll
    for (int kk = 0; kk < 2; ++kk) {
      h8 af[4], bf[4];
#pragma unroll
      for (int mf = 0; mf < 4; ++mf)
        af[mf] = *(const h8*)&Asm[mf * 16 + l15][kk * 32 + lhi * 8];
#pragma unroll
      for (int nf = 0; nf < 4; ++nf) {
        int rB = wv * 64 + nf * 16 + l15;
        bf[nf] = *(const h8*)&Bsm[rB][((kk * 4 + lhi) ^ (rB & 7)) * 8];
      }
#pragma unroll
      for (int mf = 0; mf < 4; ++mf)
#pragma unroll
        for (int nf = 0; nf < 4; ++nf)
          acc[mf][nf] = __builtin_amdgcn_mfma_f32_16x16x32_f16(af[mf], bf[nf], acc[mf][nf], 0, 0, 0);
    }
    __syncthreads();
  }

  // Epilogue: per-row sum of tanh(u)*Ve over this wave's 64 cols, then atomic.
  float vev[4], biasv[4];
#pragma unroll
  for (int nf = 0; nf < 4; ++nf) {
    int c = ncol0 + wv * 64 + nf * 16 + l15;
    vev[nf]   = Ve[c];
    biasv[nf] = bias[(size_t)bb * 512 + c];
  }
#pragma unroll
  for (int mf = 0; mf < 4; ++mf) {
#pragma unroll
    for (int j = 0; j < 4; ++j) {
      float s = 0.f;
#pragma unroll
      for (int nf = 0; nf < 4; ++nf)
        s += tanhf(acc[mf][nf][j] + biasv[nf]) * vev[nf];
#pragma unroll
      for (int m = 1; m < 16; m <<= 1) s += __shfl_xor(s, m, 64);
      if (l15 == 0) atomicAdd(&e[row0 + mf * 16 + lhi * 4 + j], s);
    }
  }
}

// ---------------------------------------------------------------------------
// Softmax over S (in place: e -> alpha). One block per batch.
// ---------------------------------------------------------------------------
__global__ void softmax_kernel(float* __restrict__ e) {
  const int b = blockIdx.x, t = threadIdx.x;   // 256 threads
  float* row = e + (size_t)b * 512;
  float v0 = row[t], v1 = row[t + 256];
  float m = fmaxf(v0, v1);
#pragma unroll
  for (int d = 1; d < 64; d <<= 1) m = fmaxf(m, __shfl_xor(m, d, 64));
  __shared__ float r1[4], r2[4];
  if ((t & 63) == 0) r1[t >> 6] = m;
  __syncthreads();
  m = fmaxf(fmaxf(r1[0], r1[1]), fmaxf(r1[2], r1[3]));
  float e0 = expf(v0 - m), e1 = expf(v1 - m);
  float s = e0 + e1;
#pragma unroll
  for (int d = 1; d < 64; d <<= 1) s += __shfl_xor(s, d, 64);
  if ((t & 63) == 0) r2[t >> 6] = s;
  __syncthreads();
  s = r2[0] + r2[1] + r2[2] + r2[3];
  float inv = 1.0f / s;
  row[t]       = e0 * inv;
  row[t + 256] = e1 * inv;
}

// ---------------------------------------------------------------------------
// context[b][hd] = sum_s alpha[b][s] * h[b][s][hd]  (s split 4-way, atomic)
// ---------------------------------------------------------------------------
__global__ __launch_bounds__(512)
void ctx_kernel(const float* __restrict__ hT, const float* __restrict__ alpha,
                float* __restrict__ out) {
  const int b  = blockIdx.x >> 2;
  const int sc = blockIdx.x & 3;
  const int hd = threadIdx.x;
  __shared__ float al[128];
  if (threadIdx.x < 128) al[threadIdx.x] = alpha[(size_t)b * 512 + sc * 128 + threadIdx.x];
  __syncthreads();
  const float* hp = hT + ((size_t)b * 512 + sc * 128) * 512 + hd;
  float acc = 0.f;
#pragma unroll 4
  for (int s = 0; s < 128; ++s) acc += al[s] * hp[(size_t)s * 512];
  atomicAdd(&out[b * 512 + hd], acc);
}

// ---------------------------------------------------------------------------
extern "C" void kernel_launch(void* const* d_in, const int* in_sizes, int n_in,
                              void* d_out, int out_size, void* d_ws, size_t ws_size,
                              hipStream_t stream) {
  const float* h  = (const float*)d_in[0];
  const float* x  = (const float*)d_in[1];
  const float* Ve = (const float*)d_in[2];
  const float* U1 = (const float*)d_in[3];
  const float* U2 = (const float*)d_in[4];
  float* out = (float*)d_out;

  // ws layout: Bws fp16 [512][1024] = 1 MB | bias f32 [128][512] = 256 KB | e f32 = 256 KB
  _Float16* Bws  = (_Float16*)d_ws;
  float*    bias = (float*)((char*)d_ws + (1u << 20));
  float*    e    = (float*)((char*)d_ws + (1u << 20) + (256u << 10));
  if (ws_size < ((1u << 20) + (512u << 10))) return;

  hipMemsetAsync(e, 0, 65536 * sizeof(float), stream);
  hipMemsetAsync(d_out, 0, 65536 * sizeof(float), stream);

  bsetup_kernel<<<256, 256, 0, stream>>>(U1, U2, Bws);
  bias_kernel<<<128, 256, 0, stream>>>(h, U1, bias);
  gemm_kernel<<<2048, 256, 0, stream>>>(h, x, Bws, bias, Ve, e);
  softmax_kernel<<<128, 256, 0, stream>>>(e);
  ctx_kernel<<<512, 512, 0, stream>>>(h, e, out);
}

// Round 2
// 220.904 us; speedup vs baseline: 2.4633x; 2.4633x over previous
//
#include <hip/hip_runtime.h>
#include <cstdint>
#include <cstddef>

// Problem: B=128, S=512, H=512
//   context[b,h] = sum_s softmax_s( sum_k tanh(u[b,s,k]) Ve[k] ) * h[b,s,h]
//   u = h@U1a^T + x@U2^T + (h_last@U1b^T broadcast over s)
// R2: zero-reg-staging GEMM. A (f32) and B (pre-swizzled fp16 tiles) both go
// global->LDS via global_load_lds; fp16 MFMA; fused tanh/Ve epilogue.

typedef _Float16 h8 __attribute__((ext_vector_type(8)));
typedef float    f4 __attribute__((ext_vector_type(4)));

#define GLOAD16(g, l)                                                          \
  __builtin_amdgcn_global_load_lds(                                            \
      (const __attribute__((address_space(1))) void*)(g),                      \
      (__attribute__((address_space(3))) void*)(l), 16, 0, 0)

// ---------------------------------------------------------------------------
// Setup: Bws2 tile-major, swizzle baked in.
// Bws2[(nt*16+kt)*256 + r][s*8..] = fp16( U[nt*256+r][ kt*64 + (s^(r&7))*8 ..+8 ] )
// where U[n][k] = k<512 ? U1[n][k] : U2[n][k-512]
// ---------------------------------------------------------------------------
__global__ void bsetup_kernel(const float* __restrict__ U1, const float* __restrict__ U2,
                              _Float16* __restrict__ Bws) {
  int g = blockIdx.x * 256 + threadIdx.x;   // 65536 threads
  int s  = g & 7;
  int r  = (g >> 3) & 255;
  int kt = (g >> 11) & 15;
  int nt = g >> 15;
  int n = nt * 256 + r;
  int k = kt * 64 + ((s ^ (r & 7)) << 3);
  const float* p = (k < 512) ? (U1 + (size_t)n * 1024 + k)
                             : (U2 + (size_t)n * 512 + (k - 512));
  float4 a = *(const float4*)p;
  float4 b = *(const float4*)(p + 4);
  _Float16 hv[8];
  hv[0]=(_Float16)a.x; hv[1]=(_Float16)a.y; hv[2]=(_Float16)a.z; hv[3]=(_Float16)a.w;
  hv[4]=(_Float16)b.x; hv[5]=(_Float16)b.y; hv[6]=(_Float16)b.z; hv[7]=(_Float16)b.w;
  *(uint4*)(Bws + ((size_t)((nt * 16 + kt) * 256 + r) << 6) + (s << 3)) = *(uint4*)hv;
}

// ---------------------------------------------------------------------------
// bias[b][n] = sum_h h[b][S-1][h] * U1[n][512+h]   (fp32, exact)
// ---------------------------------------------------------------------------
__global__ void bias_kernel(const float* __restrict__ hT, const float* __restrict__ U1,
                            float* __restrict__ bias) {
  const int b = blockIdx.x, t = threadIdx.x;
  const int l = t & 63, w = t >> 6;
  __shared__ float4 hl[128];
  if (t < 128) hl[t] = *(const float4*)(hT + ((size_t)b * 512 + 511) * 512 + t * 4);
  __syncthreads();
  for (int n = w; n < 512; n += 4) {
    const float4* ur = (const float4*)(U1 + (size_t)n * 1024 + 512);
    float4 u0 = ur[l],      u1 = ur[l + 64];
    float4 h0 = hl[l],      h1 = hl[l + 64];
    float s = u0.x*h0.x + u0.y*h0.y + u0.z*h0.z + u0.w*h0.w
            + u1.x*h1.x + u1.y*h1.y + u1.z*h1.z + u1.w*h1.w;
#pragma unroll
    for (int d = 1; d < 64; d <<= 1) s += __shfl_xor(s, d, 64);
    if (l == 0) bias[(size_t)b * 512 + n] = s;
  }
}

// ---------------------------------------------------------------------------
// Main fused GEMM: M=65536, N=512 (2 N-blocks of 256), K=1024, BK=64.
// 256 threads / 4 waves; wave tile 64x64 (4x4 16x16 frags).
// A staged f32 in LDS (slot-XOR swizzled via per-lane source addresses),
// B staged fp16 from pre-swizzled tile-major Bws2. All staging = global_load_lds.
// ---------------------------------------------------------------------------
__global__ __launch_bounds__(256, 3)
void gemm_kernel(const float* __restrict__ hT, const float* __restrict__ xT,
                 const _Float16* __restrict__ Bws, const float* __restrict__ bias,
                 const float* __restrict__ Ve, float* __restrict__ e) {
  // XCD-chunked swizzle (2048 = 8 * 256): pairs (2m,2m+1) share an A-panel
  // and land on the same XCD, temporally adjacent -> L2 reuse of A.
  const int bid  = ((int)blockIdx.x & 7) * 256 + ((int)blockIdx.x >> 3);
  const int bm   = bid >> 1;
  const int nt   = bid & 1;
  const int row0 = bm * 64;
  const int bb   = row0 >> 9;
  const int t    = threadIdx.x;
  const int l    = t & 63;
  const int wv   = t >> 6;
  const int l15  = l & 15;
  const int lhi  = l >> 4;

  __shared__ __align__(16) float    Asm[64 * 64];    // 16 KB, rows 256 B
  __shared__ __align__(16) _Float16 Bsm[256 * 64];   // 32 KB, rows 128 B

  auto STAGE = [&](int kt) {
    const float* srcA = (kt < 8) ? hT : xT;
    const int kc = (kt & 7) * 64;
    // A: 16 wave-instrs total (4 per wave); dest linear, source slot-swizzled
#pragma unroll
    for (int j = 0; j < 4; ++j) {
      int r = wv * 16 + j * 4 + (l >> 4);
      int s = l & 15;
      const float* g = srcA + (size_t)(row0 + r) * 512 + kc + ((s ^ (r & 7)) << 2);
      GLOAD16(g, &Asm[(wv * 16 + j * 4) * 64]);
    }
    // B: 32 wave-instrs total (8 per wave); tile stored exactly as LDS image
    const _Float16* tb = Bws + ((size_t)(nt * 16 + kt) << 14);
#pragma unroll
    for (int j = 0; j < 8; ++j) {
      const _Float16* g = tb + (wv * 8 + j) * 512 + l * 8;
      GLOAD16(g, &Bsm[(wv * 8 + j) * 512]);
    }
  };

  f4 acc[4][4];
#pragma unroll
  for (int mf = 0; mf < 4; ++mf)
#pragma unroll
    for (int nf = 0; nf < 4; ++nf)
      acc[mf][nf] = (f4){0.f, 0.f, 0.f, 0.f};

  STAGE(0);

  for (int kt = 0; kt < 16; ++kt) {
    __syncthreads();   // waves drain own vmcnt before barrier -> tile ready
#pragma unroll
    for (int kk = 0; kk < 2; ++kk) {
      h8 af[4], bf[4];
#pragma unroll
      for (int mf = 0; mf < 4; ++mf) {
        int rA = mf * 16 + l15;
        int c0 = kk * 8 + lhi * 2;
        const float4 a0 = *(const float4*)&Asm[rA * 64 + ((c0 ^ (rA & 7)) << 2)];
        const float4 a1 = *(const float4*)&Asm[rA * 64 + (((c0 + 1) ^ (rA & 7)) << 2)];
        h8 tf;
        tf[0]=(_Float16)a0.x; tf[1]=(_Float16)a0.y; tf[2]=(_Float16)a0.z; tf[3]=(_Float16)a0.w;
        tf[4]=(_Float16)a1.x; tf[5]=(_Float16)a1.y; tf[6]=(_Float16)a1.z; tf[7]=(_Float16)a1.w;
        af[mf] = tf;
      }
#pragma unroll
      for (int nf = 0; nf < 4; ++nf) {
        int rB = wv * 64 + nf * 16 + l15;
        int sB = kk * 4 + lhi;
        bf[nf] = *(const h8*)&Bsm[rB * 64 + ((sB ^ (rB & 7)) << 3)];
      }
#pragma unroll
      for (int mf = 0; mf < 4; ++mf)
#pragma unroll
        for (int nf = 0; nf < 4; ++nf)
          acc[mf][nf] = __builtin_amdgcn_mfma_f32_16x16x32_f16(af[mf], bf[nf], acc[mf][nf], 0, 0, 0);
    }
    __syncthreads();   // all reads done before next overwrite
    if (kt < 15) STAGE(kt + 1);
  }

  // Epilogue: e[row] += sum over this wave's 64 cols of tanh(u)*Ve
  float vev[4], biasv[4];
#pragma unroll
  for (int nf = 0; nf < 4; ++nf) {
    int c = nt * 256 + wv * 64 + nf * 16 + l15;
    vev[nf]   = Ve[c];
    biasv[nf] = bias[(size_t)bb * 512 + c];
  }
#pragma unroll
  for (int mf = 0; mf < 4; ++mf) {
#pragma unroll
    for (int j = 0; j < 4; ++j) {
      float s = 0.f;
#pragma unroll
      for (int nf = 0; nf < 4; ++nf)
        s += tanhf(acc[mf][nf][j] + biasv[nf]) * vev[nf];
#pragma unroll
      for (int m = 1; m < 16; m <<= 1) s += __shfl_xor(s, m, 64);
      if (l15 == 0) atomicAdd(&e[row0 + mf * 16 + lhi * 4 + j], s);
    }
  }
}

// ---------------------------------------------------------------------------
// Softmax over S (in place: e -> alpha). One block per batch.
// ---------------------------------------------------------------------------
__global__ void softmax_kernel(float* __restrict__ e) {
  const int b = blockIdx.x, t = threadIdx.x;   // 256 threads
  float* row = e + (size_t)b * 512;
  float v0 = row[t], v1 = row[t + 256];
  float m = fmaxf(v0, v1);
#pragma unroll
  for (int d = 1; d < 64; d <<= 1) m = fmaxf(m, __shfl_xor(m, d, 64));
  __shared__ float r1[4], r2[4];
  if ((t & 63) == 0) r1[t >> 6] = m;
  __syncthreads();
  m = fmaxf(fmaxf(r1[0], r1[1]), fmaxf(r1[2], r1[3]));
  float e0 = expf(v0 - m), e1 = expf(v1 - m);
  float s = e0 + e1;
#pragma unroll
  for (int d = 1; d < 64; d <<= 1) s += __shfl_xor(s, d, 64);
  if ((t & 63) == 0) r2[t >> 6] = s;
  __syncthreads();
  s = r2[0] + r2[1] + r2[2] + r2[3];
  float inv = 1.0f / s;
  row[t]       = e0 * inv;
  row[t + 256] = e1 * inv;
}

// ---------------------------------------------------------------------------
// context[b][hd] = sum_s alpha[b][s] * h[b][s][hd]  (s split 4-way, atomic)
// ---------------------------------------------------------------------------
__global__ __launch_bounds__(512)
void ctx_kernel(const float* __restrict__ hT, const float* __restrict__ alpha,
                float* __restrict__ out) {
  const int b  = blockIdx.x >> 2;
  const int sc = blockIdx.x & 3;
  const int hd = threadIdx.x;
  __shared__ float al[128];
  if (threadIdx.x < 128) al[threadIdx.x] = alpha[(size_t)b * 512 + sc * 128 + threadIdx.x];
  __syncthreads();
  const float* hp = hT + ((size_t)b * 512 + sc * 128) * 512 + hd;
  float acc = 0.f;
#pragma unroll 4
  for (int s = 0; s < 128; ++s) acc += al[s] * hp[(size_t)s * 512];
  atomicAdd(&out[b * 512 + hd], acc);
}

// ---------------------------------------------------------------------------
extern "C" void kernel_launch(void* const* d_in, const int* in_sizes, int n_in,
                              void* d_out, int out_size, void* d_ws, size_t ws_size,
                              hipStream_t stream) {
  const float* h  = (const float*)d_in[0];
  const float* x  = (const float*)d_in[1];
  const float* Ve = (const float*)d_in[2];
  const float* U1 = (const float*)d_in[3];
  const float* U2 = (const float*)d_in[4];
  float* out = (float*)d_out;

  // ws layout: Bws2 fp16 tile-major 1 MB | bias f32 256 KB | e f32 256 KB
  _Float16* Bws  = (_Float16*)d_ws;
  float*    bias = (float*)((char*)d_ws + (1u << 20));
  float*    e    = (float*)((char*)d_ws + (1u << 20) + (256u << 10));
  if (ws_size < ((1u << 20) + (512u << 10))) return;

  hipMemsetAsync(e, 0, 65536 * sizeof(float), stream);
  hipMemsetAsync(d_out, 0, 65536 * sizeof(float), stream);

  bsetup_kernel<<<256, 256, 0, stream>>>(U1, U2, Bws);
  bias_kernel<<<128, 256, 0, stream>>>(h, U1, bias);
  gemm_kernel<<<2048, 256, 0, stream>>>(h, x, Bws, bias, Ve, e);
  softmax_kernel<<<128, 256, 0, stream>>>(e);
  ctx_kernel<<<512, 512, 0, stream>>>(h, e, out);
}